// Round 8
// baseline (463.233 us; speedup 1.0000x reference)
//
#include <hip/hip_runtime.h>
#include <math.h>

#define SQ 96            // H == W == 96
#define CQ 256
#define HWQ 9216         // 96*96
#define PIXQ 73728       // 8*9216

typedef __attribute__((ext_vector_type(8))) __bf16 bf16x8;
typedef __attribute__((ext_vector_type(4))) float f32x4;

union FragU { uint4 u; bf16x8 b; };

// round-to-nearest-even fp32 -> bf16 (as u16 in low bits)
__device__ inline uint32_t bf16_rne_u(float f) {
  uint32_t u = __float_as_uint(f);
  return (u + 0x7FFFu + ((u >> 16) & 1u)) >> 16;
}
// split fp32 into hi (RNE bf16) + lo (truncated bf16 of residual), packed u32
__device__ inline uint32_t pack_split(float f) {
  uint32_t hi = bf16_rne_u(f);
  float rem = f - __uint_as_float(hi << 16);
  uint32_t lo = __float_as_uint(rem) >> 16;
  return hi | (lo << 16);
}

// XOR-swizzled LDS read addressing for [row][128B] tiles.  Records in global
// are LINEAR; the staging DMA permutes granules via its per-lane SOURCE
// address (granule ^= row&7), so LDS holds the swizzled image and this
// read applies the same involution.  2-way bank aliasing only.
__device__ inline const uint32_t* swzc(const uint32_t* base, int row, int colb) {
  return base + row * 32 + ((colb ^ ((row & 7) << 4)) >> 2);
}

// async global->LDS DMA, 16B per lane, lane-linear LDS dest
__device__ inline void lds_dma16(const void* g, void* l) {
  __builtin_amdgcn_global_load_lds(
      (const __attribute__((address_space(1))) uint32_t*)g,
      (__attribute__((address_space(3))) uint32_t*)l, 16, 0, 0);
}

// split 8 fp32 -> hi granule (16B) + lo granule (16B)
__device__ inline void split8(float4 va, float4 vb_, uint4& h, uint4& l) {
  uint32_t p0 = pack_split(va.x), p1 = pack_split(va.y);
  uint32_t p2 = pack_split(va.z), p3 = pack_split(va.w);
  uint32_t p4 = pack_split(vb_.x), p5 = pack_split(vb_.y);
  uint32_t p6 = pack_split(vb_.z), p7 = pack_split(vb_.w);
  h.x = (p0 & 0xFFFFu) | (p1 << 16);
  h.y = (p2 & 0xFFFFu) | (p3 << 16);
  h.z = (p4 & 0xFFFFu) | (p5 << 16);
  h.w = (p6 & 0xFFFFu) | (p7 << 16);
  l.x = (p0 >> 16) | (p1 & 0xFFFF0000u);
  l.y = (p2 >> 16) | (p3 & 0xFFFF0000u);
  l.z = (p4 >> 16) | (p5 & 0xFFFF0000u);
  l.w = (p6 >> 16) | (p7 & 0xFFFF0000u);
}

// store hi/lo granules of 8 channels into LINEAR record rec (128B: 64B hi||lo)
__device__ inline void store_g8(uint32_t* __restrict__ dst, int rec, int k8,
                                uint4 h, uint4 l) {
  uint32_t* rowp = dst + (size_t)rec * 32;
  *(uint4*)(rowp + k8 * 4) = h;
  *(uint4*)(rowp + 16 + k8 * 4) = l;
}

// ---------------------------------------------------------------------------
// Fused B-prep.  Blocks 0..255: compute G row c (G[c][cp] = sum_o w[o][c] *
// w[256+o][cp]) then pack via LDS handoff.  Blocks 256..287: pack Wv rows
// (record rows 256..511 from w rows 512..767), 8 rows per block.
// ---------------------------------------------------------------------------
__global__ __launch_bounds__(256) void prep_b_kernel(
    const float* __restrict__ w, uint32_t* __restrict__ Bps) {
  __shared__ float grow[256];
  const int blk = blockIdx.x;
  if (blk < 256) {
    const int cp = threadIdx.x;
    float acc = 0.0f;
#pragma unroll 4
    for (int o = 0; o < 256; ++o)
      acc += w[o * 256 + blk] * w[(256 + o) * 256 + cp];
    grow[cp] = acc;
    __syncthreads();
    if (threadIdx.x < 32) {
      int rem = threadIdx.x * 8;
      uint4 h, l;
      split8(*(const float4*)(grow + rem), *(const float4*)(grow + rem + 4), h, l);
      store_g8(Bps, blk * 8 + (rem >> 5), (rem & 31) >> 3, h, l);
    }
  } else {
    int r = (blk - 256) * 8 + (threadIdx.x >> 5);    // 0..255
    int rem = (threadIdx.x & 31) * 8;
    const float* s = w + (size_t)(512 + r) * 256 + rem;
    uint4 h, l;
    split8(*(const float4*)s, *(const float4*)(s + 4), h, l);
    store_g8(Bps, (256 + r) * 8 + (rem >> 5), (rem & 31) >> 3, h, l);
  }
}

// t = Wk^T bq (block 0), s = Wq^T bk (block 1).
__global__ __launch_bounds__(256) void prep_vec_kernel(
    const float* __restrict__ w, const float* __restrict__ bias,
    float* __restrict__ tvec, float* __restrict__ svec) {
  const int c = threadIdx.x;
  if (blockIdx.x == 0) {
    float t = 0.0f;
#pragma unroll 4
    for (int o = 0; o < 256; ++o) t += bias[o] * w[(256 + o) * 256 + c];
    tvec[c] = t;
  } else {
    float s = 0.0f;
#pragma unroll 4
    for (int o = 0; o < 256; ++o) s += bias[256 + o] * w[o * 256 + c];
    svec[c] = s;
  }
}

// ---------------------------------------------------------------------------
// Split x into LINEAR tile records (8 contiguous 16B stores per thread) AND
// emit per-pixel correction dots dtp = t.x, dsp = s.x (plain stores).
// One thread = one 128B record (32 ch); 8 threads = 1 pixel.
// ---------------------------------------------------------------------------
__global__ __launch_bounds__(256) void split_x_kernel(
    const float* __restrict__ x, const float* __restrict__ tvec,
    const float* __restrict__ svec, uint32_t* __restrict__ xps,
    float* __restrict__ dtp, float* __restrict__ dsp) {
  int rec = blockIdx.x * 256 + threadIdx.x;   // 0..589823
  int m = rec >> 3;                            // pixel (input order b,w,h)
  int kc = rec & 7;                            // 32-ch chunk
  const float* s = x + (size_t)m * 256 + kc * 32;
  const float* tv = tvec + kc * 32;
  const float* sv = svec + kc * 32;
  uint4 hh[4], ll[4];
  float dt = 0.0f, ds = 0.0f;
#pragma unroll
  for (int g = 0; g < 4; ++g) {
    float4 va = *(const float4*)(s + g * 8);
    float4 vb_ = *(const float4*)(s + g * 8 + 4);
    split8(va, vb_, hh[g], ll[g]);
    const float* tg = tv + g * 8;
    const float* sg = sv + g * 8;
    dt += va.x * tg[0] + va.y * tg[1] + va.z * tg[2] + va.w * tg[3]
        + vb_.x * tg[4] + vb_.y * tg[5] + vb_.z * tg[6] + vb_.w * tg[7];
    ds += va.x * sg[0] + va.y * sg[1] + va.z * sg[2] + va.w * sg[3]
        + vb_.x * sg[4] + vb_.y * sg[5] + vb_.z * sg[6] + vb_.w * sg[7];
  }
  uint32_t* rowp = xps + (size_t)rec * 32;
#pragma unroll
  for (int g = 0; g < 4; ++g) *(uint4*)(rowp + g * 4) = hh[g];
#pragma unroll
  for (int g = 0; g < 4; ++g) *(uint4*)(rowp + 16 + g * 4) = ll[g];
#pragma unroll
  for (int off = 1; off < 8; off <<= 1) {
    dt += __shfl_xor(dt, off);
    ds += __shfl_xor(ds, off);
  }
  if ((rec & 7) == 0) {
    dtp[m] = dt;
    dsp[m] = ds;
  }
}

// alpha[b,h] = sum_w dtp[b,w,h]; gamma[b,w] = sum_h dsp[b,w,h].  8 blocks.
__global__ __launch_bounds__(256) void reduce_ag_kernel(
    const float* __restrict__ dtp, const float* __restrict__ dsp,
    float* __restrict__ alpha, float* __restrict__ gamma) {
  const int b = blockIdx.x;
  const int t = threadIdx.x;
  if (t < 96) {
    float a = 0.0f;
#pragma unroll 4
    for (int wi = 0; wi < 96; ++wi) a += dtp[b * HWQ + wi * SQ + t];
    alpha[b * SQ + t] = a;
  } else if (t >= 128 && t < 224) {
    int wi = t - 128;
    float g = 0.0f;
#pragma unroll 4
    for (int hh = 0; hh < 96; ++hh) g += dsp[b * HWQ + wi * SQ + hh];
    gamma[b * SQ + wi] = g;
  }
}

// ---------------------------------------------------------------------------
// Fused GEMM: [y; v] = [G; Wv] . x   (M=73728, N=512, K=256)
// Block 128x128, 4 waves (2x2) of 64x64, 3 split-products, single-buffer LDS
// for A ONLY.  B (512 KB packed) is L2-resident and read as fragments
// DIRECTLY from global (lesson: don't LDS-stage L2-fit data); the B loads
// issue before the barrier so their latency hides under the A-DMA drain.
// XCD-chunked 1-D grid, n-fastest.  y -> linear split records; v -> bf16.
// ---------------------------------------------------------------------------
__global__ __launch_bounds__(256) void qkv_gemm_mfma(
    const uint32_t* __restrict__ xps, const uint32_t* __restrict__ Bps,
    const float* __restrict__ bias, ushort* __restrict__ yps,
    ushort* __restrict__ vb) {
  __shared__ uint32_t Apk[128 * 32];   // [m][128B = 64B hi | 64B lo], swz
  const int tid = threadIdx.x;
  const int lane = tid & 63;
  const int wid = tid >> 6;
  const int wm = wid >> 1, wn = wid & 1;
  const int lr = lane & 15, quad = lane >> 4;
  // 2304 blocks = 576 m-panels x 4 n-panels; 288 per XCD, n-fastest
  const int lin = (blockIdx.x & 7) * 288 + (blockIdx.x >> 3);
  const int m0 = (lin >> 2) * 128, n0 = (lin & 3) * 128;
  const int srow = tid >> 3;           // 0..31 (row within 32-row slab)
  const int sg = ((tid & 7) ^ (srow & 7)) * 4;   // source-side swizzle (u32)

  const uint32_t* aP = xps + (size_t)(m0 + srow) * 256 + sg;
  // per-thread B fragment base: row = n0 + wn*64 + lr, granule quad
  const uint32_t* bF = Bps + (size_t)(n0 + wn * 64 + lr) * 256 + quad * 4;

  f32x4 acc[4][4] = {};

  for (int kc = 0; kc < 8; ++kc) {
#pragma unroll
    for (int j = 0; j < 4; ++j)
      lds_dma16(aP + j * 8192 + kc * 32, &Apk[j * 1024 + tid * 4]);
    // B fragments straight from global (L2-hot); issued pre-barrier
    FragU bh[4], bl[4];
#pragma unroll
    for (int t = 0; t < 4; ++t) {
      const uint32_t* bp = bF + t * 4096 + kc * 32;   // +t*16 rows
      bh[t].u = *(const uint4*)bp;
      bl[t].u = *(const uint4*)(bp + 16);
    }
    __syncthreads();

    FragU ah[4], al[4];
#pragma unroll
    for (int t = 0; t < 4; ++t) {
      const int ra = wm * 64 + t * 16 + lr;
      ah[t].u = *(const uint4*)swzc(Apk, ra, quad * 16);
      al[t].u = *(const uint4*)swzc(Apk, ra, 64 + quad * 16);
    }
#pragma unroll
    for (int i = 0; i < 4; ++i)
#pragma unroll
      for (int j = 0; j < 4; ++j) {
        acc[i][j] = __builtin_amdgcn_mfma_f32_16x16x32_bf16(al[i].b, bh[j].b, acc[i][j], 0, 0, 0);
        acc[i][j] = __builtin_amdgcn_mfma_f32_16x16x32_bf16(ah[i].b, bl[j].b, acc[i][j], 0, 0, 0);
        acc[i][j] = __builtin_amdgcn_mfma_f32_16x16x32_bf16(ah[i].b, bh[j].b, acc[i][j], 0, 0, 0);
      }
    __syncthreads();
  }

  // epilogue: C[row=(quad*4+r)][col=lr] per 16x16 tile
  if (n0 < 256) {
    // y = G.x, no bias; LINEAR split records at input pixel order
#pragma unroll
    for (int i = 0; i < 4; ++i) {
      const int growb = m0 + wm * 64 + i * 16 + quad * 4;
#pragma unroll
      for (int r = 0; r < 4; ++r) {
        int p = growb + r;
        size_t b16 = (size_t)p * 512;        // 8 records x 64 u16
#pragma unroll
        for (int j = 0; j < 4; ++j) {
          int o = n0 + wn * 64 + j * 16 + lr;   // 0..255
          int ci = o & 31, kc = o >> 5;
          uint32_t ps = pack_split(acc[i][j][r]);
          size_t rb = b16 + (size_t)kc * 64;
          yps[rb + ci] = (ushort)ps;
          yps[rb + 32 + ci] = (ushort)(ps >> 16);
        }
      }
    }
  } else {
    // v = Wv.x + bv; bf16, h-major pixels
#pragma unroll
    for (int i = 0; i < 4; ++i) {
      const int growb = m0 + wm * 64 + i * 16 + quad * 4;
#pragma unroll
      for (int r = 0; r < 4; ++r) {
        int p = growb + r;                 // input pixel order (b, w, h)
        int b = p / HWQ;
        int rem = p - b * HWQ;
        int ww = rem / SQ;
        int hh = rem - ww * SQ;
        size_t opix = (size_t)b * HWQ + (size_t)hh * SQ + ww;   // h-major
#pragma unroll
        for (int j = 0; j < 4; ++j) {
          int o = n0 + wn * 64 + j * 16 + lr;   // 256..511
          float val = acc[i][j][r] + bias[256 + o];
          vb[opix * 256 + (o - 256)] = (ushort)bf16_rne_u(val);
        }
      }
    }
  }
}

// ---------------------------------------------------------------------------
// Attention scores from x,y fields (linear records; swizzle on DMA source).
// ONE kout per block (fine K-split for occupancy: 1536 blocks = 6/CU);
// partial 96x96 tiles to Sp[which][b][kout]; softmax reduces 96 partials.
// which=0: Sh[h1,h2] = sum_{w,c} x[h1].y[h2]   (pix = kout*96+row)
// which=1: Sw[w1,w2] = sum_{h,c} y[w1].x[w2]   (pix = row*96+kout)
// Block: M=96,N=96, 4 waves (2x2) of 48x48; 8 k-chunk iters.
// ---------------------------------------------------------------------------
__global__ __launch_bounds__(256) void attn_scores_mfma(
    const ushort* __restrict__ xf, const ushort* __restrict__ yf,
    float* __restrict__ Sp) {
  __shared__ uint32_t Xpk[96 * 32];
  __shared__ uint32_t Ypk[96 * 32];
  const int tid = threadIdx.x;
  const int lane = tid & 63;
  const int wid = tid >> 6;
  const int wm = wid >> 1, wn = wid & 1;
  const int lr = lane & 15, quad = lane >> 4;
  const int kout = blockIdx.x;       // 0..95 (w for Sh, h for Sw)
  const int b = blockIdx.y;          // 0..7
  const int which = blockIdx.z;      // 0=Sh, 1=Sw
  const ushort* Xf = which ? yf : xf;
  const ushort* Yf = which ? xf : yf;
  const int srow = tid >> 3;           // 0..31
  const int byteoff = (tid & 7) * 16;

  f32x4 acc[3][3] = {};

  for (int kc = 0; kc < 8; ++kc) {
#pragma unroll
    for (int j = 0; j < 3; ++j) {
      int row = j * 32 + srow;
      int pm = which ? (row * SQ + kout) : (kout * SQ + row);
      int pix = b * HWQ + pm;
      int nom = byteoff ^ ((row & 7) << 4);   // source-side swizzle
      size_t off = (size_t)pix * 512 + kc * 64 + (nom >> 1);
      lds_dma16(Xf + off, &Xpk[j * 1024 + tid * 4]);
      lds_dma16(Yf + off, &Ypk[j * 1024 + tid * 4]);
    }
    __syncthreads();

    FragU xh[3], xl[3], yh[3], yl[3];
#pragma unroll
    for (int t = 0; t < 3; ++t) {
      const int rx = wm * 48 + t * 16 + lr;
      xh[t].u = *(const uint4*)swzc(Xpk, rx, quad * 16);
      xl[t].u = *(const uint4*)swzc(Xpk, rx, 64 + quad * 16);
      const int ry = wn * 48 + t * 16 + lr;
      yh[t].u = *(const uint4*)swzc(Ypk, ry, quad * 16);
      yl[t].u = *(const uint4*)swzc(Ypk, ry, 64 + quad * 16);
    }
#pragma unroll
    for (int i = 0; i < 3; ++i)
#pragma unroll
      for (int j = 0; j < 3; ++j) {
        acc[i][j] = __builtin_amdgcn_mfma_f32_16x16x32_bf16(xl[i].b, yh[j].b, acc[i][j], 0, 0, 0);
        acc[i][j] = __builtin_amdgcn_mfma_f32_16x16x32_bf16(xh[i].b, yl[j].b, acc[i][j], 0, 0, 0);
        acc[i][j] = __builtin_amdgcn_mfma_f32_16x16x32_bf16(xh[i].b, yh[j].b, acc[i][j], 0, 0, 0);
      }
    __syncthreads();
  }
  float* S = Sp + ((size_t)(which * 8 + b) * SQ + kout) * (size_t)HWQ;
#pragma unroll
  for (int i = 0; i < 3; ++i)
#pragma unroll
    for (int r = 0; r < 4; ++r)
#pragma unroll
      for (int j = 0; j < 3; ++j) {
        int row = wm * 48 + i * 16 + quad * 4 + r;
        int col = wn * 48 + j * 16 + lr;
        S[(size_t)row * SQ + col] = acc[i][j][r];
      }
}

// ---------------------------------------------------------------------------
// Reduce 96 score partials + corrections, softmax over 96, emit bf16 probs.
// ---------------------------------------------------------------------------
__global__ __launch_bounds__(256) void softmax_p(
    const float* __restrict__ Sp, const float* __restrict__ alpha,
    const float* __restrict__ gamma, ushort* __restrict__ Pms,
    ushort* __restrict__ Pma) {
  const int tid = threadIdx.x;
  const int lane = tid & 63;
  const int row = blockIdx.x * 4 + (tid >> 6);   // 0..1535
  const int wsel = row >= 768;
  const int rr = row - wsel * 768;               // b*96 + (h1|w1)
  const int b = rr / SQ;
  const int hr = rr - b * SQ;
  const float* base = Sp + ((size_t)(wsel * 8 + b) * SQ) * (size_t)HWQ
                      + (size_t)hr * SQ;
  float v0 = 0.0f, s1 = 0.0f;
#pragma unroll 8
  for (int ch = 0; ch < 96; ++ch) {
    const float* p = base + (size_t)ch * HWQ;
    v0 += p[lane];
    if (lane < 32) s1 += p[64 + lane];
  }
  const float* corr = (wsel ? gamma : alpha) + b * SQ;
  v0 += corr[lane];
  ushort* q = wsel ? (Pma + (size_t)rr * SQ) : (Pms + (size_t)rr * SQ);
  float v1 = (lane < 32) ? (s1 + corr[64 + lane]) : -3.0e38f;
  float m = fmaxf(v0, v1);
#pragma unroll
  for (int off = 32; off > 0; off >>= 1) m = fmaxf(m, __shfl_xor(m, off));
  float e0 = __expf(v0 - m);
  float e1 = (lane < 32) ? __expf(v1 - m) : 0.0f;
  float s = e0 + e1;
#pragma unroll
  for (int off = 32; off > 0; off >>= 1) s += __shfl_xor(s, off);
  float inv = 1.0f / s;
  q[lane] = (ushort)bf16_rne_u(e0 * inv);
  if (lane < 32) q[64 + lane] = (ushort)bf16_rne_u(e1 * inv);
}

// ---------------------------------------------------------------------------
// Apply attention.  out: ((b*96 + w)*96 + h)*256 + c
// which=0 (xi=w): O[h][c]  = sum_k Pms[b,h,k] * V[b,k,xi,c]
// which=1 (xi=h): O[w][c] += sum_k Pma[b,w,k] * V[b,xi,k,c]
// Grid (96 xi, 8 b, 2 c-half) = 1536 blocks.  M=96, N=128, K=96.
// 4 waves (2x2) of 48x64.  V transposed into LDS [c][k] per 32-k chunk via
// 2x2 micro-blocks; k-slot XOR swizzle (slot = k2 ^ (c2&12)) keeps b128
// reads aligned+ordered while cutting transpose-write conflicts 16->4-way.
// ---------------------------------------------------------------------------
__global__ __launch_bounds__(256) void attn_apply_mfma(
    const ushort* __restrict__ vb, const ushort* __restrict__ P,
    float* __restrict__ out, const int which) {
  __shared__ ushort Vt[128 * 40];      // [c-local][k-pair slots 16 + pad 4]
  const int tid = threadIdx.x;
  const int lane = tid & 63;
  const int wid = tid >> 6;
  const int wm = wid >> 1, wn = wid & 1;
  const int lr = lane & 15, quad = lane >> 4;
  const int xi = blockIdx.x;           // w (which=0) or h (which=1)
  const int b = blockIdx.y;
  const int ch = blockIdx.z;           // c-half

  f32x4 acc[3][4] = {};

  for (int k0 = 0; k0 < 96; k0 += 32) {
    // stage V-tile (32 k x 128 c) transposed via 2x2 micro-blocks
#pragma unroll
    for (int j = 0; j < 4; ++j) {
      int bi = j * 256 + tid;          // 0..1023
      int c2 = bi & 63;                // c-pair in half
      int k2 = bi >> 6;                // k-pair 0..15
      int k = k0 + k2 * 2;
      int c = ch * 128 + c2 * 2;
      size_t r0, r1;
      if (which == 0) {
        r0 = ((size_t)b * HWQ + (size_t)k * SQ + xi) * CQ + c;
        r1 = r0 + (size_t)SQ * CQ;
      } else {
        r0 = ((size_t)b * HWQ + (size_t)xi * SQ + k) * CQ + c;
        r1 = r0 + CQ;
      }
      uint32_t a0 = *(const uint32_t*)(vb + r0);       // V[k][c], V[k][c+1]
      uint32_t a1 = *(const uint32_t*)(vb + r1);       // V[k+1][c], V[k+1][c+1]
      uint32_t w0 = (a0 & 0xFFFFu) | (a1 << 16);       // Vt[c][k..k+1]
      uint32_t w1 = (a0 >> 16) | (a1 & 0xFFFF0000u);   // Vt[c+1][k..k+1]
      int cl = c2 * 2;
      int slot = k2 ^ (c2 & 12);       // key = (row>>1)&12, same for cl, cl+1
      *(uint32_t*)&Vt[cl * 40 + slot * 2] = w0;
      *(uint32_t*)&Vt[(cl + 1) * 40 + slot * 2] = w1;
    }
    __syncthreads();
    // A frags straight from global P (L1/L2-hot, reused by 192 blocks)
    FragU a[3];
#pragma unroll
    for (int t = 0; t < 3; ++t) {
      int row = wm * 48 + t * 16 + lr;
      a[t].u = *(const uint4*)(P + ((size_t)b * SQ + row) * SQ + k0 + quad * 8);
    }
#pragma unroll
    for (int j = 0; j < 4; ++j) {
      int cb = wn * 64 + j * 16 + lr;                // local c row
      int slot = (quad * 4) ^ ((cb >> 1) & 12);      // aligned 4-slot block
      FragU bf;
      bf.u = *(const uint4*)&Vt[cb * 40 + slot * 2];
#pragma unroll
      for (int i = 0; i < 3; ++i)
        acc[i][j] = __builtin_amdgcn_mfma_f32_16x16x32_bf16(a[i].b, bf.b, acc[i][j], 0, 0, 0);
    }
    __syncthreads();
  }

#pragma unroll
  for (int i = 0; i < 3; ++i)
#pragma unroll
    for (int r = 0; r < 4; ++r) {
      int mrow = wm * 48 + i * 16 + quad * 4 + r;
      size_t obase = which ? (((size_t)b * SQ + mrow) * SQ + xi) * CQ
                           : (((size_t)b * SQ + xi) * SQ + mrow) * CQ;
#pragma unroll
      for (int j = 0; j < 4; ++j) {
        int c = ch * 128 + wn * 64 + j * 16 + lr;
        if (which == 0) out[obase + c] = acc[i][j][r];
        else            out[obase + c] += acc[i][j][r];
      }
    }
}

// ---------------------------------------------------------------------------
extern "C" void kernel_launch(void* const* d_in, const int* in_sizes, int n_in,
                              void* d_out, int out_size, void* d_ws,
                              size_t ws_size, hipStream_t stream) {
  const float* x = (const float*)d_in[0];      // (8,96,96,256) = (B,W,H,C)
  const float* w = (const float*)d_in[1];      // (768,256)
  const float* bias = (const float*)d_in[2];   // (768,)
  float* out = (float*)d_out;                  // (8,96,96,256) = (B,W,H,C)

  // workspace (~172 MB)
  ushort* yps = (ushort*)d_ws;                           // 73728*512 u16
  ushort* vb  = yps + (size_t)PIXQ * 512;                // 73728*256 u16
  ushort* Pms = vb + (size_t)PIXQ * 256;                 // 73728 u16
  ushort* Pma = Pms + PIXQ;                              // 73728 u16
  float*  Sp  = (float*)(Pma + PIXQ);                    // 2*8*96*9216 f32
  uint32_t* Bps = (uint32_t*)(Sp + (size_t)2 * 8 * SQ * HWQ);  // 512*256 u32
  float* tvec = (float*)(Bps + 512 * 256);               // 256
  float* svec = tvec + 256;                              // 256
  float* alpha = svec + 256;                             // 768
  float* gamma = alpha + 768;                            // 768
  float* dtp = gamma + 768;                              // 73728
  float* dsp = dtp + PIXQ;                               // 73728

  // x tile records live in d_out; alive split -> scores; apply overwrites
  // d_out only after scores has consumed xps.
  uint32_t* xps = (uint32_t*)d_out;

  prep_b_kernel<<<dim3(288), 256, 0, stream>>>(w, Bps);
  prep_vec_kernel<<<dim3(2), 256, 0, stream>>>(w, bias, tvec, svec);
  split_x_kernel<<<dim3(2304), 256, 0, stream>>>(x, tvec, svec, xps, dtp, dsp);
  reduce_ag_kernel<<<dim3(8), 256, 0, stream>>>(dtp, dsp, alpha, gamma);
  qkv_gemm_mfma<<<dim3(2304), 256, 0, stream>>>(xps, Bps, bias, yps, vb);
  attn_scores_mfma<<<dim3(96, 8, 2), 256, 0, stream>>>((const ushort*)xps, yps, Sp);
  softmax_p<<<dim3(384), 256, 0, stream>>>(Sp, alpha, gamma, Pms, Pma);
  attn_apply_mfma<<<dim3(96, 8, 2), 256, 0, stream>>>(vb, Pms, out, 0);
  attn_apply_mfma<<<dim3(96, 8, 2), 256, 0, stream>>>(vb, Pma, out, 1);
}

// Round 9
// 381.834 us; speedup vs baseline: 1.2132x; 1.2132x over previous
//
#include <hip/hip_runtime.h>
#include <math.h>

#define SQ 96            // H == W == 96
#define CQ 256
#define HWQ 9216         // 96*96
#define PIXQ 73728       // 8*9216

typedef __attribute__((ext_vector_type(8))) __bf16 bf16x8;
typedef __attribute__((ext_vector_type(4))) float f32x4;

union FragU { uint4 u; bf16x8 b; };

// round-to-nearest-even fp32 -> bf16 (as u16 in low bits)
__device__ inline uint32_t bf16_rne_u(float f) {
  uint32_t u = __float_as_uint(f);
  return (u + 0x7FFFu + ((u >> 16) & 1u)) >> 16;
}
// split fp32 into hi (RNE bf16) + lo (truncated bf16 of residual), packed u32
__device__ inline uint32_t pack_split(float f) {
  uint32_t hi = bf16_rne_u(f);
  float rem = f - __uint_as_float(hi << 16);
  uint32_t lo = __float_as_uint(rem) >> 16;
  return hi | (lo << 16);
}

// XOR-swizzled LDS read addressing for [row][128B] tiles.  Records in global
// are LINEAR; the staging DMA permutes granules via its per-lane SOURCE
// address (granule ^= row&7), so LDS holds the swizzled image and this
// read applies the same involution.  2-way bank aliasing only.
__device__ inline const uint32_t* swzc(const uint32_t* base, int row, int colb) {
  return base + row * 32 + ((colb ^ ((row & 7) << 4)) >> 2);
}

// async global->LDS DMA, 16B per lane, lane-linear LDS dest
__device__ inline void lds_dma16(const void* g, void* l) {
  __builtin_amdgcn_global_load_lds(
      (const __attribute__((address_space(1))) uint32_t*)g,
      (__attribute__((address_space(3))) uint32_t*)l, 16, 0, 0);
}

// split 8 fp32 -> hi granule (16B) + lo granule (16B)
__device__ inline void split8(float4 va, float4 vb_, uint4& h, uint4& l) {
  uint32_t p0 = pack_split(va.x), p1 = pack_split(va.y);
  uint32_t p2 = pack_split(va.z), p3 = pack_split(va.w);
  uint32_t p4 = pack_split(vb_.x), p5 = pack_split(vb_.y);
  uint32_t p6 = pack_split(vb_.z), p7 = pack_split(vb_.w);
  h.x = (p0 & 0xFFFFu) | (p1 << 16);
  h.y = (p2 & 0xFFFFu) | (p3 << 16);
  h.z = (p4 & 0xFFFFu) | (p5 << 16);
  h.w = (p6 & 0xFFFFu) | (p7 << 16);
  l.x = (p0 >> 16) | (p1 & 0xFFFF0000u);
  l.y = (p2 >> 16) | (p3 & 0xFFFF0000u);
  l.z = (p4 >> 16) | (p5 & 0xFFFF0000u);
  l.w = (p6 >> 16) | (p7 & 0xFFFF0000u);
}

// store hi/lo granules of 8 channels into LINEAR record rec (128B: 64B hi||lo)
__device__ inline void store_g8(uint32_t* __restrict__ dst, int rec, int k8,
                                uint4 h, uint4 l) {
  uint32_t* rowp = dst + (size_t)rec * 32;
  *(uint4*)(rowp + k8 * 4) = h;
  *(uint4*)(rowp + 16 + k8 * 4) = l;
}

// ---------------------------------------------------------------------------
// Fused B-prep.  Blocks 0..255: compute G row c (G[c][cp] = sum_o w[o][c] *
// w[256+o][cp]) then pack via LDS handoff.  Blocks 256..287: pack Wv rows
// (record rows 256..511 from w rows 512..767), 8 rows per block.
// ---------------------------------------------------------------------------
__global__ __launch_bounds__(256) void prep_b_kernel(
    const float* __restrict__ w, uint32_t* __restrict__ Bps) {
  __shared__ float grow[256];
  const int blk = blockIdx.x;
  if (blk < 256) {
    const int cp = threadIdx.x;
    float acc = 0.0f;
#pragma unroll 4
    for (int o = 0; o < 256; ++o)
      acc += w[o * 256 + blk] * w[(256 + o) * 256 + cp];
    grow[cp] = acc;
    __syncthreads();
    if (threadIdx.x < 32) {
      int rem = threadIdx.x * 8;
      uint4 h, l;
      split8(*(const float4*)(grow + rem), *(const float4*)(grow + rem + 4), h, l);
      store_g8(Bps, blk * 8 + (rem >> 5), (rem & 31) >> 3, h, l);
    }
  } else {
    int r = (blk - 256) * 8 + (threadIdx.x >> 5);    // 0..255
    int rem = (threadIdx.x & 31) * 8;
    const float* s = w + (size_t)(512 + r) * 256 + rem;
    uint4 h, l;
    split8(*(const float4*)s, *(const float4*)(s + 4), h, l);
    store_g8(Bps, (256 + r) * 8 + (rem >> 5), (rem & 31) >> 3, h, l);
  }
}

// t = Wk^T bq (block 0), s = Wq^T bk (block 1).
__global__ __launch_bounds__(256) void prep_vec_kernel(
    const float* __restrict__ w, const float* __restrict__ bias,
    float* __restrict__ tvec, float* __restrict__ svec) {
  const int c = threadIdx.x;
  if (blockIdx.x == 0) {
    float t = 0.0f;
#pragma unroll 4
    for (int o = 0; o < 256; ++o) t += bias[o] * w[(256 + o) * 256 + c];
    tvec[c] = t;
  } else {
    float s = 0.0f;
#pragma unroll 4
    for (int o = 0; o < 256; ++o) s += bias[256 + o] * w[o * 256 + c];
    svec[c] = s;
  }
}

// ---------------------------------------------------------------------------
// Split x into LINEAR tile records (8 contiguous 16B stores per thread) AND
// emit per-pixel correction dots dtp = t.x, dsp = s.x (plain stores).
// One thread = one 128B record (32 ch); 8 threads = 1 pixel.
// ---------------------------------------------------------------------------
__global__ __launch_bounds__(256) void split_x_kernel(
    const float* __restrict__ x, const float* __restrict__ tvec,
    const float* __restrict__ svec, uint32_t* __restrict__ xps,
    float* __restrict__ dtp, float* __restrict__ dsp) {
  int rec = blockIdx.x * 256 + threadIdx.x;   // 0..589823
  int m = rec >> 3;                            // pixel (input order b,w,h)
  int kc = rec & 7;                            // 32-ch chunk
  const float* s = x + (size_t)m * 256 + kc * 32;
  const float* tv = tvec + kc * 32;
  const float* sv = svec + kc * 32;
  uint4 hh[4], ll[4];
  float dt = 0.0f, ds = 0.0f;
#pragma unroll
  for (int g = 0; g < 4; ++g) {
    float4 va = *(const float4*)(s + g * 8);
    float4 vb_ = *(const float4*)(s + g * 8 + 4);
    split8(va, vb_, hh[g], ll[g]);
    const float* tg = tv + g * 8;
    const float* sg = sv + g * 8;
    dt += va.x * tg[0] + va.y * tg[1] + va.z * tg[2] + va.w * tg[3]
        + vb_.x * tg[4] + vb_.y * tg[5] + vb_.z * tg[6] + vb_.w * tg[7];
    ds += va.x * sg[0] + va.y * sg[1] + va.z * sg[2] + va.w * sg[3]
        + vb_.x * sg[4] + vb_.y * sg[5] + vb_.z * sg[6] + vb_.w * sg[7];
  }
  uint32_t* rowp = xps + (size_t)rec * 32;
#pragma unroll
  for (int g = 0; g < 4; ++g) *(uint4*)(rowp + g * 4) = hh[g];
#pragma unroll
  for (int g = 0; g < 4; ++g) *(uint4*)(rowp + 16 + g * 4) = ll[g];
#pragma unroll
  for (int off = 1; off < 8; off <<= 1) {
    dt += __shfl_xor(dt, off);
    ds += __shfl_xor(ds, off);
  }
  if ((rec & 7) == 0) {
    dtp[m] = dt;
    dsp[m] = ds;
  }
}

// alpha[b,h] = sum_w dtp[b,w,h]; gamma[b,w] = sum_h dsp[b,w,h].  8 blocks.
__global__ __launch_bounds__(256) void reduce_ag_kernel(
    const float* __restrict__ dtp, const float* __restrict__ dsp,
    float* __restrict__ alpha, float* __restrict__ gamma) {
  const int b = blockIdx.x;
  const int t = threadIdx.x;
  if (t < 96) {
    float a = 0.0f;
#pragma unroll 4
    for (int wi = 0; wi < 96; ++wi) a += dtp[b * HWQ + wi * SQ + t];
    alpha[b * SQ + t] = a;
  } else if (t >= 128 && t < 224) {
    int wi = t - 128;
    float g = 0.0f;
#pragma unroll 4
    for (int hh = 0; hh < 96; ++hh) g += dsp[b * HWQ + wi * SQ + hh];
    gamma[b * SQ + wi] = g;
  }
}

// ---------------------------------------------------------------------------
// Fused GEMM: [y; v] = [G; Wv] . x   (M=73728, N=512, K=256)
// Block 128x128, 4 waves (2x2) of 64x64, 3 split-products, single-buffer LDS
// for BOTH A and B (r8 lesson: B-direct-from-global loses 35 us — LDS
// staging converts the 16B-scatter into one coalesced DMA).
// XCD-chunked 1-D grid, n-fastest.  y -> linear split records; v -> bf16.
// ---------------------------------------------------------------------------
__global__ __launch_bounds__(256) void qkv_gemm_mfma(
    const uint32_t* __restrict__ xps, const uint32_t* __restrict__ Bps,
    const float* __restrict__ bias, ushort* __restrict__ yps,
    ushort* __restrict__ vb) {
  __shared__ uint32_t Apk[128 * 32];   // [m][128B = 64B hi | 64B lo], swz
  __shared__ uint32_t Bpk[128 * 32];
  const int tid = threadIdx.x;
  const int lane = tid & 63;
  const int wid = tid >> 6;
  const int wm = wid >> 1, wn = wid & 1;
  const int lr = lane & 15, quad = lane >> 4;
  // 2304 blocks = 576 m-panels x 4 n-panels; 288 per XCD, n-fastest
  const int lin = (blockIdx.x & 7) * 288 + (blockIdx.x >> 3);
  const int m0 = (lin >> 2) * 128, n0 = (lin & 3) * 128;
  const int srow = tid >> 3;           // 0..31 (row within 32-row slab)
  const int sg = ((tid & 7) ^ (srow & 7)) * 4;   // source-side swizzle (u32)

  const uint32_t* aP = xps + (size_t)(m0 + srow) * 256 + sg;
  const uint32_t* bP = Bps + (size_t)(n0 + srow) * 256 + sg;

  f32x4 acc[4][4] = {};

  for (int kc = 0; kc < 8; ++kc) {
#pragma unroll
    for (int j = 0; j < 4; ++j) {
      lds_dma16(aP + j * 8192 + kc * 32, &Apk[j * 1024 + tid * 4]);
      lds_dma16(bP + j * 8192 + kc * 32, &Bpk[j * 1024 + tid * 4]);
    }
    __syncthreads();

    FragU ah[4], al[4], bh[4], bl[4];
#pragma unroll
    for (int t = 0; t < 4; ++t) {
      const int ra = wm * 64 + t * 16 + lr;
      ah[t].u = *(const uint4*)swzc(Apk, ra, quad * 16);
      al[t].u = *(const uint4*)swzc(Apk, ra, 64 + quad * 16);
      const int rb = wn * 64 + t * 16 + lr;
      bh[t].u = *(const uint4*)swzc(Bpk, rb, quad * 16);
      bl[t].u = *(const uint4*)swzc(Bpk, rb, 64 + quad * 16);
    }
#pragma unroll
    for (int i = 0; i < 4; ++i)
#pragma unroll
      for (int j = 0; j < 4; ++j) {
        acc[i][j] = __builtin_amdgcn_mfma_f32_16x16x32_bf16(al[i].b, bh[j].b, acc[i][j], 0, 0, 0);
        acc[i][j] = __builtin_amdgcn_mfma_f32_16x16x32_bf16(ah[i].b, bl[j].b, acc[i][j], 0, 0, 0);
        acc[i][j] = __builtin_amdgcn_mfma_f32_16x16x32_bf16(ah[i].b, bh[j].b, acc[i][j], 0, 0, 0);
      }
    __syncthreads();
  }

  // epilogue: C[row=(quad*4+r)][col=lr] per 16x16 tile
  if (n0 < 256) {
    // y = G.x, no bias; LINEAR split records at input pixel order
#pragma unroll
    for (int i = 0; i < 4; ++i) {
      const int growb = m0 + wm * 64 + i * 16 + quad * 4;
#pragma unroll
      for (int r = 0; r < 4; ++r) {
        int p = growb + r;
        size_t b16 = (size_t)p * 512;        // 8 records x 64 u16
#pragma unroll
        for (int j = 0; j < 4; ++j) {
          int o = n0 + wn * 64 + j * 16 + lr;   // 0..255
          int ci = o & 31, kc = o >> 5;
          uint32_t ps = pack_split(acc[i][j][r]);
          size_t rb = b16 + (size_t)kc * 64;
          yps[rb + ci] = (ushort)ps;
          yps[rb + 32 + ci] = (ushort)(ps >> 16);
        }
      }
    }
  } else {
    // v = Wv.x + bv; bf16, h-major pixels
#pragma unroll
    for (int i = 0; i < 4; ++i) {
      const int growb = m0 + wm * 64 + i * 16 + quad * 4;
#pragma unroll
      for (int r = 0; r < 4; ++r) {
        int p = growb + r;                 // input pixel order (b, w, h)
        int b = p / HWQ;
        int rem = p - b * HWQ;
        int ww = rem / SQ;
        int hh = rem - ww * SQ;
        size_t opix = (size_t)b * HWQ + (size_t)hh * SQ + ww;   // h-major
#pragma unroll
        for (int j = 0; j < 4; ++j) {
          int o = n0 + wn * 64 + j * 16 + lr;   // 256..511
          float val = acc[i][j][r] + bias[256 + o];
          vb[opix * 256 + (o - 256)] = (ushort)bf16_rne_u(val);
        }
      }
    }
  }
}

// ---------------------------------------------------------------------------
// Attention scores from x,y fields (linear records; swizzle on DMA source).
// K split across 32 chunks (r8 lesson: finer 96-way split costs more in Sp
// traffic than it gains in occupancy); partials to Sp; softmax reduces.
// which=0: Sh[h1,h2] = sum_{w,c} x[h1].y[h2]   (pix = kout*96+row)
// which=1: Sw[w1,w2] = sum_{h,c} y[w1].x[w2]   (pix = row*96+kout)
// Block: M=96,N=96, 4 waves (2x2) of 48x48.
// ---------------------------------------------------------------------------
__global__ __launch_bounds__(256) void attn_scores_mfma(
    const ushort* __restrict__ xf, const ushort* __restrict__ yf,
    float* __restrict__ Sp) {
  __shared__ uint32_t Xpk[96 * 32];
  __shared__ uint32_t Ypk[96 * 32];
  const int tid = threadIdx.x;
  const int lane = tid & 63;
  const int wid = tid >> 6;
  const int wm = wid >> 1, wn = wid & 1;
  const int lr = lane & 15, quad = lane >> 4;
  const int chunk = blockIdx.x;      // 0..31 (3 kouts each)
  const int b = blockIdx.y;          // 0..7
  const int which = blockIdx.z;      // 0=Sh, 1=Sw
  const ushort* Xf = which ? yf : xf;
  const ushort* Yf = which ? xf : yf;
  const int srow = tid >> 3;           // 0..31
  const int byteoff = (tid & 7) * 16;

  f32x4 acc[3][3] = {};

  for (int it = 0; it < 24; ++it) {
    int kout = chunk * 3 + (it >> 3);     // w (Sh) or h (Sw)
    int kc = it & 7;
#pragma unroll
    for (int j = 0; j < 3; ++j) {
      int row = j * 32 + srow;
      int pm = which ? (row * SQ + kout) : (kout * SQ + row);
      int pix = b * HWQ + pm;
      int nom = byteoff ^ ((row & 7) << 4);   // source-side swizzle
      size_t off = (size_t)pix * 512 + kc * 64 + (nom >> 1);
      lds_dma16(Xf + off, &Xpk[j * 1024 + tid * 4]);
      lds_dma16(Yf + off, &Ypk[j * 1024 + tid * 4]);
    }
    __syncthreads();

    FragU xh[3], xl[3], yh[3], yl[3];
#pragma unroll
    for (int t = 0; t < 3; ++t) {
      const int rx = wm * 48 + t * 16 + lr;
      xh[t].u = *(const uint4*)swzc(Xpk, rx, quad * 16);
      xl[t].u = *(const uint4*)swzc(Xpk, rx, 64 + quad * 16);
      const int ry = wn * 48 + t * 16 + lr;
      yh[t].u = *(const uint4*)swzc(Ypk, ry, quad * 16);
      yl[t].u = *(const uint4*)swzc(Ypk, ry, 64 + quad * 16);
    }
#pragma unroll
    for (int i = 0; i < 3; ++i)
#pragma unroll
      for (int j = 0; j < 3; ++j) {
        acc[i][j] = __builtin_amdgcn_mfma_f32_16x16x32_bf16(xl[i].b, yh[j].b, acc[i][j], 0, 0, 0);
        acc[i][j] = __builtin_amdgcn_mfma_f32_16x16x32_bf16(xh[i].b, yl[j].b, acc[i][j], 0, 0, 0);
        acc[i][j] = __builtin_amdgcn_mfma_f32_16x16x32_bf16(xh[i].b, yh[j].b, acc[i][j], 0, 0, 0);
      }
    __syncthreads();
  }
  float* S = Sp + ((size_t)(which * 8 + b) * 32 + chunk) * (size_t)HWQ;
#pragma unroll
  for (int i = 0; i < 3; ++i)
#pragma unroll
    for (int r = 0; r < 4; ++r)
#pragma unroll
      for (int j = 0; j < 3; ++j) {
        int row = wm * 48 + i * 16 + quad * 4 + r;
        int col = wn * 48 + j * 16 + lr;
        S[(size_t)row * SQ + col] = acc[i][j][r];
      }
}

// ---------------------------------------------------------------------------
// Reduce 32 score partials + corrections, softmax over 96, emit bf16 probs.
// ---------------------------------------------------------------------------
__global__ __launch_bounds__(256) void softmax_p(
    const float* __restrict__ Sp, const float* __restrict__ alpha,
    const float* __restrict__ gamma, ushort* __restrict__ Pms,
    ushort* __restrict__ Pma) {
  const int tid = threadIdx.x;
  const int lane = tid & 63;
  const int row = blockIdx.x * 4 + (tid >> 6);   // 0..1535
  const int wsel = row >= 768;
  const int rr = row - wsel * 768;               // b*96 + (h1|w1)
  const int b = rr / SQ;
  const int hr = rr - b * SQ;
  const float* base = Sp + ((size_t)(wsel * 8 + b) * 32) * (size_t)HWQ
                      + (size_t)hr * SQ;
  float v0 = 0.0f, s1 = 0.0f;
#pragma unroll 4
  for (int ch = 0; ch < 32; ++ch) {
    const float* p = base + (size_t)ch * HWQ;
    v0 += p[lane];
    if (lane < 32) s1 += p[64 + lane];
  }
  const float* corr = (wsel ? gamma : alpha) + b * SQ;
  v0 += corr[lane];
  ushort* q = wsel ? (Pma + (size_t)rr * SQ) : (Pms + (size_t)rr * SQ);
  float v1 = (lane < 32) ? (s1 + corr[64 + lane]) : -3.0e38f;
  float m = fmaxf(v0, v1);
#pragma unroll
  for (int off = 32; off > 0; off >>= 1) m = fmaxf(m, __shfl_xor(m, off));
  float e0 = __expf(v0 - m);
  float e1 = (lane < 32) ? __expf(v1 - m) : 0.0f;
  float s = e0 + e1;
#pragma unroll
  for (int off = 32; off > 0; off >>= 1) s += __shfl_xor(s, off);
  float inv = 1.0f / s;
  q[lane] = (ushort)bf16_rne_u(e0 * inv);
  if (lane < 32) q[64 + lane] = (ushort)bf16_rne_u(e1 * inv);
}

// ---------------------------------------------------------------------------
// Apply attention.  Final out: ((b*96 + w)*96 + h)*256 + c  (fp32)
// which=0 (xi=w): Oms[h][c] = sum_k Pms[b,h,k] * V[b,k,xi,c]  -> bf16 buffer
// which=1 (xi=h): out[w][c] = Oms[w][c] + sum_k Pma[b,w,k] * V[b,xi,k,c]
// (bf16 intermediate halves the inter-apply traffic vs fp32 RMW; error
//  ~2e-3 absolute against threshold 0.16.)
// Grid (96 xi, 8 b, 2 c-half) = 1536 blocks.  M=96, N=128, K=96.
// 4 waves (2x2) of 48x64.  V transposed into LDS [c][k] per 32-k chunk via
// 2x2 micro-blocks; k-slot XOR swizzle (slot = k2 ^ (c2&12)) keeps b128
// reads aligned+ordered while cutting transpose-write conflicts 16->4-way.
// ---------------------------------------------------------------------------
__global__ __launch_bounds__(256) void attn_apply_mfma(
    const ushort* __restrict__ vb, const ushort* __restrict__ P,
    ushort* __restrict__ oms, float* __restrict__ out, const int which) {
  __shared__ ushort Vt[128 * 40];      // [c-local][k-pair slots 16 + pad 4]
  const int tid = threadIdx.x;
  const int lane = tid & 63;
  const int wid = tid >> 6;
  const int wm = wid >> 1, wn = wid & 1;
  const int lr = lane & 15, quad = lane >> 4;
  const int xi = blockIdx.x;           // w (which=0) or h (which=1)
  const int b = blockIdx.y;
  const int ch = blockIdx.z;           // c-half

  f32x4 acc[3][4] = {};

  for (int k0 = 0; k0 < 96; k0 += 32) {
    // stage V-tile (32 k x 128 c) transposed via 2x2 micro-blocks
#pragma unroll
    for (int j = 0; j < 4; ++j) {
      int bi = j * 256 + tid;          // 0..1023
      int c2 = bi & 63;                // c-pair in half
      int k2 = bi >> 6;                // k-pair 0..15
      int k = k0 + k2 * 2;
      int c = ch * 128 + c2 * 2;
      size_t r0, r1;
      if (which == 0) {
        r0 = ((size_t)b * HWQ + (size_t)k * SQ + xi) * CQ + c;
        r1 = r0 + (size_t)SQ * CQ;
      } else {
        r0 = ((size_t)b * HWQ + (size_t)xi * SQ + k) * CQ + c;
        r1 = r0 + CQ;
      }
      uint32_t a0 = *(const uint32_t*)(vb + r0);       // V[k][c], V[k][c+1]
      uint32_t a1 = *(const uint32_t*)(vb + r1);       // V[k+1][c], V[k+1][c+1]
      uint32_t w0 = (a0 & 0xFFFFu) | (a1 << 16);       // Vt[c][k..k+1]
      uint32_t w1 = (a0 >> 16) | (a1 & 0xFFFF0000u);   // Vt[c+1][k..k+1]
      int cl = c2 * 2;
      int slot = k2 ^ (c2 & 12);       // key = (row>>1)&12, same for cl, cl+1
      *(uint32_t*)&Vt[cl * 40 + slot * 2] = w0;
      *(uint32_t*)&Vt[(cl + 1) * 40 + slot * 2] = w1;
    }
    __syncthreads();
    // A frags straight from global P (L1/L2-hot, reused by 192 blocks)
    FragU a[3];
#pragma unroll
    for (int t = 0; t < 3; ++t) {
      int row = wm * 48 + t * 16 + lr;
      a[t].u = *(const uint4*)(P + ((size_t)b * SQ + row) * SQ + k0 + quad * 8);
    }
#pragma unroll
    for (int j = 0; j < 4; ++j) {
      int cb = wn * 64 + j * 16 + lr;                // local c row
      int slot = (quad * 4) ^ ((cb >> 1) & 12);      // aligned 4-slot block
      FragU bf;
      bf.u = *(const uint4*)&Vt[cb * 40 + slot * 2];
#pragma unroll
      for (int i = 0; i < 3; ++i)
        acc[i][j] = __builtin_amdgcn_mfma_f32_16x16x32_bf16(a[i].b, bf.b, acc[i][j], 0, 0, 0);
    }
    __syncthreads();
  }

#pragma unroll
  for (int i = 0; i < 3; ++i)
#pragma unroll
    for (int r = 0; r < 4; ++r) {
      int mrow = wm * 48 + i * 16 + quad * 4 + r;
#pragma unroll
      for (int j = 0; j < 4; ++j) {
        int c = ch * 128 + wn * 64 + j * 16 + lr;
        if (which == 0) {
          // pixel (b, w=xi, h=mrow)
          size_t obase = (((size_t)b * SQ + xi) * SQ + mrow) * CQ;
          oms[obase + c] = (ushort)bf16_rne_u(acc[i][j][r]);
        } else {
          // pixel (b, w=mrow, h=xi)
          size_t obase = (((size_t)b * SQ + mrow) * SQ + xi) * CQ;
          uint32_t mu = oms[obase + c];
          out[obase + c] = acc[i][j][r] + __uint_as_float(mu << 16);
        }
      }
    }
}

// ---------------------------------------------------------------------------
extern "C" void kernel_launch(void* const* d_in, const int* in_sizes, int n_in,
                              void* d_out, int out_size, void* d_ws,
                              size_t ws_size, hipStream_t stream) {
  const float* x = (const float*)d_in[0];      // (8,96,96,256) = (B,W,H,C)
  const float* w = (const float*)d_in[1];      // (768,256)
  const float* bias = (const float*)d_in[2];   // (768,)
  float* out = (float*)d_out;                  // (8,96,96,256) = (B,W,H,C)

  // workspace (~172 MB)
  ushort* yps = (ushort*)d_ws;                           // 73728*512 u16
  ushort* vb  = yps + (size_t)PIXQ * 512;                // 73728*256 u16
  ushort* oms = vb + (size_t)PIXQ * 256;                 // 73728*256 u16
  ushort* Pms = oms + (size_t)PIXQ * 256;                // 73728 u16
  ushort* Pma = Pms + PIXQ;                              // 73728 u16
  float*  Sp  = (float*)(Pma + PIXQ);                    // 2*8*32*9216 f32
  uint32_t* Bps = (uint32_t*)(Sp + (size_t)2 * 8 * 32 * HWQ);  // 512*256 u32
  float* tvec = (float*)(Bps + 512 * 256);               // 256
  float* svec = tvec + 256;                              // 256
  float* alpha = svec + 256;                             // 768
  float* gamma = alpha + 768;                            // 768
  float* dtp = gamma + 768;                              // 73728
  float* dsp = dtp + PIXQ;                               // 73728

  // x tile records live in d_out; alive split -> scores; apply overwrites
  // d_out only in the which=1 pass, after scores has consumed xps.
  uint32_t* xps = (uint32_t*)d_out;

  prep_b_kernel<<<dim3(288), 256, 0, stream>>>(w, Bps);
  prep_vec_kernel<<<dim3(2), 256, 0, stream>>>(w, bias, tvec, svec);
  split_x_kernel<<<dim3(2304), 256, 0, stream>>>(x, tvec, svec, xps, dtp, dsp);
  reduce_ag_kernel<<<dim3(8), 256, 0, stream>>>(dtp, dsp, alpha, gamma);
  qkv_gemm_mfma<<<dim3(2304), 256, 0, stream>>>(xps, Bps, bias, yps, vb);
  attn_scores_mfma<<<dim3(32, 8, 2), 256, 0, stream>>>((const ushort*)xps, yps, Sp);
  softmax_p<<<dim3(384), 256, 0, stream>>>(Sp, alpha, gamma, Pms, Pma);
  attn_apply_mfma<<<dim3(96, 8, 2), 256, 0, stream>>>(vb, Pms, oms, out, 0);
  attn_apply_mfma<<<dim3(96, 8, 2), 256, 0, stream>>>(vb, Pma, oms, out, 1);
}